// Round 3
// baseline (221.744 us; speedup 1.0000x reference)
//
#include <hip/hip_runtime.h>
#include <hip/hip_bf16.h>

// RelationalMemoryCoreCell on MI355X (gfx950).
// B=256, S=16, H=8, HS=128, D=1024, M=1024, R=B*S=4096.
//
// Pipeline (3 launches):
//   k_prep      : [0,128)    x-proj GEMM K-split2 -> part fp32 (2 partials)
//                 [128,1152) transpose 4 weights (Wg,Wuf,Wui,Wuo) -> wt bf16
//                 [1152,2176) cast h->hbf (ushort8 stores)
//   k_attn      : m_state + (part0+part1+b_emb) -> mpb bf16
//   k_gemm_fused: per block: 128x64 output tile, ALL 4 planes
//                 (f,i,o: A=hbf; g: A=mpb), K=1024, BK=64, dbuf LDS,
//                 counted vmcnt(8) + raw s_barrier, T2 xor-swizzle.
//                 Epilogue fused in-block via LDS round-trip -> out_mem/out_hid.
//
// Workspace (32 MB):
//   [ 0, 8MB): part fp32 [2][4][256][1024]  (ks, which: dense|xf|xi|xo)
//   [ 8,16MB): hbf bf16 [4096][1024]
//   [16,24MB): mpb bf16 [4096][1024]
//   [24,32MB): wt bf16 4 x [1024][1024]: Wg,Wuf,Wui,Wuo

typedef __hip_bfloat16 bf16;
typedef __bf16 bf16x8 __attribute__((ext_vector_type(8)));
typedef float  f32x4  __attribute__((ext_vector_type(4)));
typedef unsigned short u16x8 __attribute__((ext_vector_type(8)));

__device__ __forceinline__ float b2f(bf16 x) { return __bfloat162float(x); }
__device__ __forceinline__ bf16  f2b(float x) { return __float2bfloat16(x); }
__device__ __forceinline__ unsigned short fbits(float x) {
    bf16 b = __float2bfloat16(x);
    return *(unsigned short*)&b;
}
__device__ __forceinline__ float bu2f(unsigned short u) {
    unsigned int x = ((unsigned int)u) << 16;
    float f;
    __builtin_memcpy(&f, &x, 4);
    return f;
}
__device__ __forceinline__ float sig(float x) { return 1.0f / (1.0f + __expf(-x)); }
__device__ __forceinline__ float ftanh(float x) {
    return 1.0f - 2.0f / (1.0f + __expf(2.0f * x));
}

__device__ __forceinline__ void gl_lds16(const void* g, void* l) {
    __builtin_amdgcn_global_load_lds(
        (const __attribute__((address_space(1))) void*)g,
        (__attribute__((address_space(3))) void*)l,
        16, 0, 0);
}

// ---------------------------------------------------------------------------
// k_prep
// ---------------------------------------------------------------------------
__global__ __launch_bounds__(256) void k_prep(
    const float* __restrict__ W_g, const float* __restrict__ W_uf,
    const float* __restrict__ W_ui, const float* __restrict__ W_uo,
    const float* __restrict__ W_emb, const float* __restrict__ W_wf,
    const float* __restrict__ W_wi, const float* __restrict__ W_wo,
    const float* __restrict__ h_state, const float* __restrict__ inputs,
    bf16* __restrict__ wt, bf16* __restrict__ hbf, float* __restrict__ part)
{
    __shared__ __align__(16) char sbuf[32768];
    const int blk = blockIdx.x;
    const int tid = threadIdx.x;

    if (blk < 128) {
        // ---- x-proj: 128x128 tile, K-split 2 (K=512 per block) ----
        const float* Wsrc4[4] = {W_emb, W_wf, W_wi, W_wo};
        const int ks = blk & 1;
        const int nt = (blk >> 1) & 31;
        const int mt = blk >> 6;
        const int which = nt >> 3;
        const int n0 = (nt & 7) * 128;
        const int m0 = mt * 128;
        const int kbase = ks * 512;
        const float* Wsrc = Wsrc4[which];
        char* LA = sbuf;            // bf16 [128 rows][64 k], row stride 128B
        char* LB = sbuf + 16384;    // bf16 [128 n]  [64 k], row stride 128B

        const int wv = tid >> 6, lane = tid & 63;
        const int mrow = lane & 15, q = lane >> 4;
        const int rb = (wv & 1) * 64, cb = (wv >> 1) * 64;

        const f32x4 zero4 = {0.0f, 0.0f, 0.0f, 0.0f};
        f32x4 acc[4][4];
        #pragma unroll
        for (int i = 0; i < 4; ++i)
            #pragma unroll
            for (int j = 0; j < 4; ++j) acc[i][j] = zero4;

        for (int s = 0; s < 8; ++s) {
            const int k0 = kbase + s * 64;
            #pragma unroll
            for (int r = 0; r < 8; ++r) {
                int lin = r * 256 + tid;
                int row = lin >> 4, f4 = lin & 15;
                float4 v = *(const float4*)(inputs + (size_t)(m0 + row) * 1024 + k0 + f4 * 4);
                ushort4 p;
                p.x = fbits(v.x); p.y = fbits(v.y); p.z = fbits(v.z); p.w = fbits(v.w);
                *(ushort4*)(LA + row * 128 + ((f4 * 8) ^ ((row & 7) << 4))) = p;
            }
            #pragma unroll
            for (int r = 0; r < 2; ++r) {
                int lin = r * 256 + tid;
                int kq = lin >> 5, cq = lin & 31;
                const float* wp = Wsrc + (size_t)(k0 + kq * 4) * 1024 + n0 + cq * 4;
                float4 v0 = *(const float4*)(wp);
                float4 v1 = *(const float4*)(wp + 1024);
                float4 v2 = *(const float4*)(wp + 2048);
                float4 v3 = *(const float4*)(wp + 3072);
                const float* e0 = (const float*)&v0;
                const float* e1 = (const float*)&v1;
                const float* e2 = (const float*)&v2;
                const float* e3 = (const float*)&v3;
                #pragma unroll
                for (int j = 0; j < 4; ++j) {
                    int c = cq * 4 + j;
                    ushort4 p;
                    p.x = fbits(e0[j]); p.y = fbits(e1[j]);
                    p.z = fbits(e2[j]); p.w = fbits(e3[j]);
                    *(ushort4*)(LB + c * 128 + ((kq * 8) ^ ((c & 7) << 4))) = p;
                }
            }
            __syncthreads();
            #pragma unroll
            for (int kk = 0; kk < 2; ++kk) {
                const int kb = kk * 64 + q * 16;
                bf16x8 afr[4], bfr[4];
                #pragma unroll
                for (int i = 0; i < 4; ++i) {
                    int row = rb + i * 16 + mrow;
                    afr[i] = *(const bf16x8*)(LA + row * 128 + (kb ^ ((row & 7) << 4)));
                }
                #pragma unroll
                for (int j = 0; j < 4; ++j) {
                    int n = cb + j * 16 + mrow;
                    bfr[j] = *(const bf16x8*)(LB + n * 128 + (kb ^ ((n & 7) << 4)));
                }
                #pragma unroll
                for (int i = 0; i < 4; ++i)
                    #pragma unroll
                    for (int j = 0; j < 4; ++j)
                        acc[i][j] = __builtin_amdgcn_mfma_f32_16x16x32_bf16(afr[i], bfr[j], acc[i][j], 0, 0, 0);
            }
            __syncthreads();
        }
        float* P = part + ((size_t)(ks * 4 + which) * 256) * 1024;
        #pragma unroll
        for (int j = 0; j < 4; ++j) {
            const int colp = n0 + cb + j * 16 + mrow;
            #pragma unroll
            for (int i = 0; i < 4; ++i)
                #pragma unroll
                for (int r = 0; r < 4; ++r) {
                    const int row = m0 + rb + i * 16 + q * 4 + r;
                    P[(size_t)row * 1024 + colp] = acc[i][j][r];
                }
        }
    } else if (blk < 1152) {
        // ---- transpose Wg,Wuf,Wui,Wuo -> wt planes 0..3 (64x64 tiles) ----
        const float* Ws[4] = {W_g, W_uf, W_ui, W_uo};
        const int t = blk - 128;
        const int plane = t >> 8;
        const int tt = t & 255;
        const int kb = (tt >> 4) * 64;
        const int nb = (tt & 15) * 64;
        const float* W = Ws[plane];
        bf16* Wt = wt + (size_t)plane * (1024 * 1024);
        float (*tl)[65] = (float (*)[65])sbuf;     // [64 k][65 n] padded

        #pragma unroll
        for (int it = 0; it < 4; ++it) {
            int lin = it * 256 + tid;
            int kr = lin >> 4, n4 = lin & 15;
            *(float4*)&tl[kr][n4 * 4] =
                *(const float4*)(W + (size_t)(kb + kr) * 1024 + nb + n4 * 4);
        }
        __syncthreads();
        #pragma unroll
        for (int it = 0; it < 2; ++it) {
            int lin = it * 256 + tid;
            int n = lin >> 3, k8 = (lin & 7) * 8;
            u16x8 p;
            #pragma unroll
            for (int j = 0; j < 8; ++j) p[j] = fbits(tl[k8 + j][n]);
            *(u16x8*)(Wt + (size_t)(nb + n) * 1024 + kb + k8) = p;
        }
    } else {
        // ---- cast h_state -> hbf, 16 elems/thread, ushort8 stores ----
        const int e = blk - 1152;
        size_t idx = ((size_t)e * 256 + tid) * 16;
        #pragma unroll
        for (int hh = 0; hh < 2; ++hh) {
            float4 a = *(const float4*)(h_state + idx + hh * 8);
            float4 b = *(const float4*)(h_state + idx + hh * 8 + 4);
            u16x8 p;
            p[0] = fbits(a.x); p[1] = fbits(a.y); p[2] = fbits(a.z); p[3] = fbits(a.w);
            p[4] = fbits(b.x); p[5] = fbits(b.y); p[6] = fbits(b.z); p[7] = fbits(b.w);
            *(u16x8*)(hbf + idx + hh * 8) = p;
        }
    }
}

// ---------------------------------------------------------------------------
// attention per (b,h) -> mpb bf16  (sums dense partials + b_emb)
// ---------------------------------------------------------------------------
__global__ __launch_bounds__(256) void k_attn(
    const float* __restrict__ m_state,
    const float* __restrict__ part,
    const float* __restrict__ b_emb,
    bf16* __restrict__ mp)
{
    const int b = blockIdx.x >> 3;
    const int h = blockIdx.x & 7;
    const int tid = threadIdx.x;

    __shared__ float kv[17][132];
    __shared__ float sc[16][18];

    for (int idx = tid; idx < 17 * 32; idx += 256) {
        int r = idx >> 5, d4 = idx & 31;
        float4 v;
        if (r < 16) {
            v = *(const float4*)&m_state[(size_t)(b * 16 + r) * 1024 + h * 128 + d4 * 4];
        } else {
            float4 v0 = *(const float4*)&part[(size_t)b * 1024 + h * 128 + d4 * 4];
            float4 v1 = *(const float4*)&part[(size_t)(4 * 256 + b) * 1024 + h * 128 + d4 * 4];
            float4 be = *(const float4*)&b_emb[h * 128 + d4 * 4];
            v.x = v0.x + v1.x + be.x;
            v.y = v0.y + v1.y + be.y;
            v.z = v0.z + v1.z + be.z;
            v.w = v0.w + v1.w + be.w;
        }
        *(float4*)&kv[r][d4 * 4] = v;
    }
    __syncthreads();

    for (int p = tid; p < 16 * 17; p += 256) {
        int qi = p / 17, ki = p % 17;
        float dx = 0.f, dy = 0.f, dz = 0.f, dw = 0.f;
        #pragma unroll 8
        for (int d4 = 0; d4 < 32; ++d4) {
            float4 a = *(const float4*)&kv[qi][d4 * 4];
            float4 c = *(const float4*)&kv[ki][d4 * 4];
            dx += a.x * c.x; dy += a.y * c.y; dz += a.z * c.z; dw += a.w * c.w;
        }
        sc[qi][ki] = (dx + dy + dz + dw) * 0.0883883476483184f;
    }
    __syncthreads();

    if (tid < 16) {
        float mx = -1e30f;
        for (int k = 0; k < 17; ++k) mx = fmaxf(mx, sc[tid][k]);
        float s = 0.0f;
        for (int k = 0; k < 17; ++k) { float e = __expf(sc[tid][k] - mx); sc[tid][k] = e; s += e; }
        float inv = 1.0f / s;
        for (int k = 0; k < 17; ++k) sc[tid][k] *= inv;
    }
    __syncthreads();

    for (int p = tid; p < 16 * 32; p += 256) {
        int qi = p >> 5, d4 = p & 31;
        float sx = 0.f, sy = 0.f, sz = 0.f, sw = 0.f;
        #pragma unroll
        for (int k = 0; k < 17; ++k) {
            float w = sc[qi][k];
            float4 v = *(const float4*)&kv[k][d4 * 4];
            sx += w * v.x; sy += w * v.y; sz += w * v.z; sw += w * v.w;
        }
        float4 base = *(const float4*)&kv[qi][d4 * 4];
        size_t off = (size_t)(b * 16 + qi) * 1024 + h * 128 + d4 * 4;
        mp[off + 0] = f2b(base.x + sx);
        mp[off + 1] = f2b(base.y + sy);
        mp[off + 2] = f2b(base.z + sz);
        mp[off + 3] = f2b(base.w + sw);
    }
}

// ---------------------------------------------------------------------------
// epilogue scalar math
// ---------------------------------------------------------------------------
__device__ __forceinline__ void epi1(
    float m, float mpv, float f_, float i_, float o_, float g_,
    float xf, float xi, float xo, float bg, float bfv, float biv, float bov,
    float& om, float& oh)
{
    float mp2 = g_ + bg + mpv;
    float fg = sig(f_ + bfv + xf);
    float ig = sig(i_ + biv + xi);
    float og = sig(o_ + bov + xo);
    om = sig(m * fg + 1.0f) + mp2 * sig(ig);
    oh = ftanh(m) * sig(og);
}

// ---------------------------------------------------------------------------
// Fused GEMM+epilogue. Grid 512 = 32 row-tiles x 16 col-tiles.
// Block: 128 rows x 64 cols, all 4 planes (f,i,o: A=hbf; g: A=mpb), K=1024.
// 512 thr (8 waves: plane p=wv>>1, row-half rb=(wv&1)*64; wave tile 64x64).
// LDS dbuf 2 x 64KB: sH[128][128B] @0, sM @16K, sB[4][64][128B] @32K.
// Counted vmcnt(8) + raw s_barrier, xor-swizzle (same scheme as validated).
// Epilogue: acc -> sO bf16 [4][128][72] LDS round-trip -> gates -> fp32 out.
// ---------------------------------------------------------------------------
__global__ __launch_bounds__(512, 1) void k_gemm_fused(
    const bf16* __restrict__ hbf,
    const bf16* __restrict__ mpb,
    const bf16* __restrict__ wt,
    const float* __restrict__ m_state,
    const float* __restrict__ part,
    const float* __restrict__ b_g, const float* __restrict__ b_uf,
    const float* __restrict__ b_ui, const float* __restrict__ b_uo,
    float* __restrict__ out_mem, float* __restrict__ out_hid)
{
    extern __shared__ __align__(16) char smem[];   // 128 KB dynamic

    // XCD swizzle: each XCD owns 2 col-tiles (1MB of B stays L2-resident)
    const int bid = blockIdx.x;
    const int xcd = bid & 7;
    const int idx = bid >> 3;                  // 0..63
    const int cx = xcd * 2 + (idx & 1);        // 0..15
    const int ry = idx >> 1;                   // 0..31
    const int m0 = ry * 128;
    const int n0 = cx * 64;

    const int wv = threadIdx.x >> 6;
    const int lane = threadIdx.x & 63;
    const int r8 = lane >> 3, c8 = lane & 7;
    const int mrow = lane & 15, q = lane >> 4;
    const int p = wv >> 1;                     // plane: 0=f,1=i,2=o,3=g
    const int rb = (wv & 1) * 64;              // row half

    // B plane sources in compute order f,i,o,g
    const bf16* wp0 = wt + (size_t)1 * 1048576;   // W_uf
    const bf16* wp1 = wt + (size_t)2 * 1048576;   // W_ui
    const bf16* wp2 = wt + (size_t)3 * 1048576;   // W_uo
    const bf16* wp3 = wt;                          // W_g

    const f32x4 zero4 = {0.0f, 0.0f, 0.0f, 0.0f};
    f32x4 acc[4][4];
    #pragma unroll
    for (int i = 0; i < 4; ++i)
        #pragma unroll
        for (int j = 0; j < 4; ++j) acc[i][j] = zero4;

    // stage one K-tile (64 k) into buffer buf: 8 gl_lds16 per thread
    auto STAGE = [&](int buf, int k0) {
        char* sH = smem + buf * 65536;
        char* sM = sH + 16384;
        char* sB = sH + 32768;
        #pragma unroll
        for (int t = 0; t < 2; ++t) {
            const int rr = wv * 16 + t * 8 + r8;      // 0..127
            gl_lds16(hbf + (size_t)(m0 + rr) * 1024 + k0 + (c8 ^ r8) * 8,
                     sH + rr * 128 - r8 * 128 + r8 * 128); // linear: base + lane*16
            gl_lds16(mpb + (size_t)(m0 + rr) * 1024 + k0 + (c8 ^ r8) * 8,
                     sM + rr * 128 - r8 * 128 + r8 * 128);
        }
        {
            const int cc = wv * 8 + r8;               // 0..63
            gl_lds16(wp0 + (size_t)(n0 + cc) * 1024 + k0 + (c8 ^ r8) * 8, sB + 0 * 8192 + cc * 128);
            gl_lds16(wp1 + (size_t)(n0 + cc) * 1024 + k0 + (c8 ^ r8) * 8, sB + 1 * 8192 + cc * 128);
            gl_lds16(wp2 + (size_t)(n0 + cc) * 1024 + k0 + (c8 ^ r8) * 8, sB + 2 * 8192 + cc * 128);
            gl_lds16(wp3 + (size_t)(n0 + cc) * 1024 + k0 + (c8 ^ r8) * 8, sB + 3 * 8192 + cc * 128);
        }
    };

    STAGE(0, 0);

    #pragma unroll 2
    for (int step = 0; step < 16; ++step) {
        const int cur = step & 1;
        if (step < 15) {
            STAGE(cur ^ 1, (step + 1) * 64);
            asm volatile("s_waitcnt vmcnt(8)" ::: "memory");   // prev tile landed
        } else {
            asm volatile("s_waitcnt vmcnt(0)" ::: "memory");
        }
        __builtin_amdgcn_s_barrier();
        __builtin_amdgcn_sched_barrier(0);

        const char* sA = smem + cur * 65536 + (p == 3 ? 16384 : 0);  // sH or sM
        const char* sBp = smem + cur * 65536 + 32768 + p * 8192;
        #pragma unroll
        for (int kk = 0; kk < 2; ++kk) {
            const int kb = kk * 64 + q * 16;          // byte offset in 128B row
            bf16x8 afr[4], bfr[4];
            #pragma unroll
            for (int i = 0; i < 4; ++i) {
                const int row = rb + i * 16 + mrow;
                afr[i] = *(const bf16x8*)(sA + row * 128 + (kb ^ ((row & 7) << 4)));
            }
            #pragma unroll
            for (int j = 0; j < 4; ++j) {
                const int n = j * 16 + mrow;
                bfr[j] = *(const bf16x8*)(sBp + n * 128 + (kb ^ ((n & 7) << 4)));
            }
            #pragma unroll
            for (int i = 0; i < 4; ++i)
                #pragma unroll
                for (int j = 0; j < 4; ++j)
                    acc[i][j] = __builtin_amdgcn_mfma_f32_16x16x32_bf16(afr[i], bfr[j], acc[i][j], 0, 0, 0);
        }
        __builtin_amdgcn_sched_barrier(0);
        __builtin_amdgcn_s_barrier();
    }

    // ---- epilogue: acc -> sO (bf16, padded stride 72) -> gates -> out ----
    __syncthreads();
    bf16* sO = (bf16*)smem;
    const int OS = 72;                 // row stride (elems): 144B = 36 words, %32=4
    const int PS = 128 * 72;           // plane stride (elems)
    #pragma unroll
    for (int i = 0; i < 4; ++i)
        #pragma unroll
        for (int j = 0; j < 4; ++j)
            #pragma unroll
            for (int r = 0; r < 4; ++r) {
                const int row = rb + i * 16 + q * 4 + r;
                const int col = j * 16 + mrow;
                sO[p * PS + row * OS + col] = f2b(acc[i][j][r]);
            }
    __syncthreads();

    const int t = threadIdx.x;
    const int erow = t >> 2;           // 0..127
    const int ecol = (t & 3) * 16;     // 0,16,32,48
    const int grow = m0 + erow;
    const int gcol = n0 + ecol;
    const int bb = grow >> 4;

    const float* ms  = m_state + (size_t)grow * 1024 + gcol;
    const bf16*  mpp = mpb + (size_t)grow * 1024 + gcol;
    const bf16*  sOr = sO + erow * OS + ecol;
    const float* px  = part + (size_t)bb * 1024 + gcol;
    float* pom = out_mem + (size_t)grow * 1024 + gcol;
    float* poh = out_hid + (size_t)grow * 1024 + gcol;

    #pragma unroll
    for (int u = 0; u < 4; ++u) {
        float4 m4 = *(const float4*)(ms + u * 4);
        ushort4 mpu = *(const ushort4*)(mpp + u * 4);
        ushort4 fu = *(const ushort4*)(sOr + 0 * PS + u * 4);
        ushort4 iu = *(const ushort4*)(sOr + 1 * PS + u * 4);
        ushort4 ou = *(const ushort4*)(sOr + 2 * PS + u * 4);
        ushort4 gu = *(const ushort4*)(sOr + 3 * PS + u * 4);

        float4 xfa = *(const float4*)(px + 1 * 262144 + u * 4);
        float4 xfb = *(const float4*)(px + 5 * 262144 + u * 4);
        float4 xia = *(const float4*)(px + 2 * 262144 + u * 4);
        float4 xib = *(const float4*)(px + 6 * 262144 + u * 4);
        float4 xoa = *(const float4*)(px + 3 * 262144 + u * 4);
        float4 xob = *(const float4*)(px + 7 * 262144 + u * 4);

        float4 bg4 = *(const float4*)(b_g  + gcol + u * 4);
        float4 bf4 = *(const float4*)(b_uf + gcol + u * 4);
        float4 bi4 = *(const float4*)(b_ui + gcol + u * 4);
        float4 bo4 = *(const float4*)(b_uo + gcol + u * 4);

        float4 om, oh;
        epi1(m4.x, bu2f(mpu.x), bu2f(fu.x), bu2f(iu.x), bu2f(ou.x), bu2f(gu.x),
             xfa.x + xfb.x, xia.x + xib.x, xoa.x + xob.x,
             bg4.x, bf4.x, bi4.x, bo4.x, om.x, oh.x);
        epi1(m4.y, bu2f(mpu.y), bu2f(fu.y), bu2f(iu.y), bu2f(ou.y), bu2f(gu.y),
             xfa.y + xfb.y, xia.y + xib.y, xoa.y + xob.y,
             bg4.y, bf4.y, bi4.y, bo4.y, om.y, oh.y);
        epi1(m4.z, bu2f(mpu.z), bu2f(fu.z), bu2f(iu.z), bu2f(ou.z), bu2f(gu.z),
             xfa.z + xfb.z, xia.z + xib.z, xoa.z + xob.z,
             bg4.z, bf4.z, bi4.z, bo4.z, om.z, oh.z);
        epi1(m4.w, bu2f(mpu.w), bu2f(fu.w), bu2f(iu.w), bu2f(ou.w), bu2f(gu.w),
             xfa.w + xfb.w, xia.w + xib.w, xoa.w + xob.w,
             bg4.w, bf4.w, bi4.w, bo4.w, om.w, oh.w);

        *(float4*)(pom + u * 4) = om;
        *(float4*)(poh + u * 4) = oh;
    }
}

extern "C" void kernel_launch(void* const* d_in, const int* in_sizes, int n_in,
                              void* d_out, int out_size, void* d_ws, size_t ws_size,
                              hipStream_t stream)
{
    const float* inputs  = (const float*)d_in[0];
    const float* h_state = (const float*)d_in[1];
    const float* m_state = (const float*)d_in[2];
    const float* W_emb   = (const float*)d_in[3];
    const float* b_emb   = (const float*)d_in[4];
    const float* W_g     = (const float*)d_in[5];
    const float* b_g     = (const float*)d_in[6];
    const float* W_wf    = (const float*)d_in[7];
    const float* W_wi    = (const float*)d_in[8];
    const float* W_wo    = (const float*)d_in[9];
    const float* W_uf    = (const float*)d_in[10];
    const float* b_uf    = (const float*)d_in[11];
    const float* W_ui    = (const float*)d_in[12];
    const float* b_ui    = (const float*)d_in[13];
    const float* W_uo    = (const float*)d_in[14];
    const float* b_uo    = (const float*)d_in[15];

    char* wsb = (char*)d_ws;
    float* part = (float*)wsb;                           // 8 MB
    bf16*  hbf  = (bf16*)(wsb + 8u  * 1048576u);         // 8 MB
    bf16*  mpb  = (bf16*)(wsb + 16u * 1048576u);         // 8 MB
    bf16*  wt   = (bf16*)(wsb + 24u * 1048576u);         // 8 MB (4 planes)

    float* out_mem = (float*)d_out;
    float* out_hid = out_mem + (size_t)4096 * 1024;

    // prep: 128 x-proj + 1024 transpose + 1024 h-cast
    k_prep<<<dim3(2176), dim3(256), 0, stream>>>(
        W_g, W_uf, W_ui, W_uo, W_emb, W_wf, W_wi, W_wo,
        h_state, inputs, wt, hbf, part);

    // attention -> mpb
    k_attn<<<dim3(256 * 8), dim3(256), 0, stream>>>(m_state, part, b_emb, mpb);

    // fused GEMM + epilogue -> outputs (512 blocks, 512 thr, 128 KB dyn LDS)
    k_gemm_fused<<<dim3(512), dim3(512), 131072, stream>>>(
        hbf, mpb, wt, m_state, part,
        b_g, b_uf, b_ui, b_uo, out_mem, out_hid);
}

// Round 4
// 210.254 us; speedup vs baseline: 1.0546x; 1.0546x over previous
//
#include <hip/hip_runtime.h>
#include <hip/hip_bf16.h>

// RelationalMemoryCoreCell on MI355X (gfx950).
// B=256, S=16, H=8, HS=128, D=1024, M=1024, R=B*S=4096.
//
// Pipeline (4 launches):
//   k_prep     : [0,256)    x-proj GEMM 128x64 tiles, K-split2 -> part fp32
//                [256,1280) transpose 4 weights (Wg,Wuf,Wui,Wuo) -> wt bf16
//                [1280,2304) cast h->hbf (ushort8 stores)
//   k_attn     : m_state + (part0+part1+b_emb) -> mpb bf16
//   k_gemm_big : unified 4096x4096x1024: gates (A=hbf, Wuf/Wui/Wuo) -> pre,
//                g-plane (A=mpb, Wg) -> preg. 256^2 tile, BK=64, dbuf LDS,
//                counted vmcnt(8) + raw s_barrier, T2 xor-swizzle.
//                C-write via LDS round-trip -> coalesced ushort8 stores.
//   k_epi      : elementwise gates -> out_mem / out_hid (sums x-partials)
//
// Workspace (64 MB):
//   [ 0, 8MB): part fp32 [2][4][256][1024]  (ks, which: dense|xf|xi|xo)
//   [ 8,16MB): hbf bf16 [4096][1024]
//   [16,24MB): mpb bf16 [4096][1024]
//   [24,32MB): wt bf16 4 x [1024][1024]: Wg,Wuf,Wui,Wuo
//   [32,56MB): pre bf16 3 x [4096][1024]  (f,i,o)
//   [56,64MB): preg bf16 [4096][1024]

typedef __hip_bfloat16 bf16;
typedef __bf16 bf16x8 __attribute__((ext_vector_type(8)));
typedef float  f32x4  __attribute__((ext_vector_type(4)));
typedef unsigned short u16x8 __attribute__((ext_vector_type(8)));

__device__ __forceinline__ float b2f(bf16 x) { return __bfloat162float(x); }
__device__ __forceinline__ bf16  f2b(float x) { return __float2bfloat16(x); }
__device__ __forceinline__ unsigned short fbits(float x) {
    bf16 b = __float2bfloat16(x);
    return *(unsigned short*)&b;
}
__device__ __forceinline__ float sig(float x) { return 1.0f / (1.0f + __expf(-x)); }
__device__ __forceinline__ float ftanh(float x) {
    return 1.0f - 2.0f / (1.0f + __expf(2.0f * x));
}

__device__ __forceinline__ void gl_lds16(const void* g, void* l) {
    __builtin_amdgcn_global_load_lds(
        (const __attribute__((address_space(1))) void*)g,
        (__attribute__((address_space(3))) void*)l,
        16, 0, 0);
}

__device__ __forceinline__ float4 ld_bf4(const bf16* p) {
    ushort4 u = *(const ushort4*)p;
    float4 r;
    r.x = b2f(*(const bf16*)&u.x);
    r.y = b2f(*(const bf16*)&u.y);
    r.z = b2f(*(const bf16*)&u.z);
    r.w = b2f(*(const bf16*)&u.w);
    return r;
}

// ---------------------------------------------------------------------------
// k_prep
// ---------------------------------------------------------------------------
__global__ __launch_bounds__(256) void k_prep(
    const float* __restrict__ W_g, const float* __restrict__ W_uf,
    const float* __restrict__ W_ui, const float* __restrict__ W_uo,
    const float* __restrict__ W_emb, const float* __restrict__ W_wf,
    const float* __restrict__ W_wi, const float* __restrict__ W_wo,
    const float* __restrict__ h_state, const float* __restrict__ inputs,
    bf16* __restrict__ wt, bf16* __restrict__ hbf, float* __restrict__ part)
{
    __shared__ __align__(16) char sbuf[32768];
    const int blk = blockIdx.x;
    const int tid = threadIdx.x;

    if (blk < 256) {
        // ---- x-proj: 128x64 tile, K-split 2 (K=512 per block), 1 blk/CU ----
        const float* Wsrc4[4] = {W_emb, W_wf, W_wi, W_wo};
        const int ks = blk & 1;
        const int mt = (blk >> 1) & 1;
        const int nt = blk >> 2;            // 0..63
        const int which = nt >> 4;
        const int n0 = (nt & 15) * 64;
        const int m0 = mt * 128;
        const int kbase = ks * 512;
        const float* Wsrc = Wsrc4[which];
        char* LA = sbuf;            // bf16 [128 rows][64 k], row stride 128B
        char* LB = sbuf + 16384;    // bf16 [64 n]   [64 k], row stride 128B

        const int wv = tid >> 6, lane = tid & 63;
        const int mrow = lane & 15, q = lane >> 4;
        const int rb = (wv & 1) * 64, cb = (wv >> 1) * 32;

        const f32x4 zero4 = {0.0f, 0.0f, 0.0f, 0.0f};
        f32x4 acc[4][2];
        #pragma unroll
        for (int i = 0; i < 4; ++i)
            #pragma unroll
            for (int j = 0; j < 2; ++j) acc[i][j] = zero4;

        for (int s = 0; s < 8; ++s) {
            const int k0 = kbase + s * 64;
            // A: x fp32 -> bf16 LDS (swizzled writes, k-contiguous quads)
            #pragma unroll
            for (int r = 0; r < 8; ++r) {
                int lin = r * 256 + tid;
                int row = lin >> 4, f4 = lin & 15;
                float4 v = *(const float4*)(inputs + (size_t)(m0 + row) * 1024 + k0 + f4 * 4);
                ushort4 p;
                p.x = fbits(v.x); p.y = fbits(v.y); p.z = fbits(v.z); p.w = fbits(v.w);
                *(ushort4*)(LA + row * 128 + ((f4 * 8) ^ ((row & 7) << 4))) = p;
            }
            // B: W fp32 [K][N] -> transposed bf16 LDS via 4x4 micro-transpose
            {
                int kq = tid >> 4, cq = tid & 15;     // 16 k-quads x 16 col-quads
                const float* wp = Wsrc + (size_t)(k0 + kq * 4) * 1024 + n0 + cq * 4;
                float4 v0 = *(const float4*)(wp);
                float4 v1 = *(const float4*)(wp + 1024);
                float4 v2 = *(const float4*)(wp + 2048);
                float4 v3 = *(const float4*)(wp + 3072);
                const float* e0 = (const float*)&v0;
                const float* e1 = (const float*)&v1;
                const float* e2 = (const float*)&v2;
                const float* e3 = (const float*)&v3;
                #pragma unroll
                for (int j = 0; j < 4; ++j) {
                    int c = cq * 4 + j;
                    ushort4 p;
                    p.x = fbits(e0[j]); p.y = fbits(e1[j]);
                    p.z = fbits(e2[j]); p.w = fbits(e3[j]);
                    *(ushort4*)(LB + c * 128 + ((kq * 8) ^ ((c & 7) << 4))) = p;
                }
            }
            __syncthreads();
            #pragma unroll
            for (int kk = 0; kk < 2; ++kk) {
                const int kb = kk * 64 + q * 16;
                bf16x8 afr[4], bfr[2];
                #pragma unroll
                for (int i = 0; i < 4; ++i) {
                    int row = rb + i * 16 + mrow;
                    afr[i] = *(const bf16x8*)(LA + row * 128 + (kb ^ ((row & 7) << 4)));
                }
                #pragma unroll
                for (int j = 0; j < 2; ++j) {
                    int n = cb + j * 16 + mrow;
                    bfr[j] = *(const bf16x8*)(LB + n * 128 + (kb ^ ((n & 7) << 4)));
                }
                #pragma unroll
                for (int i = 0; i < 4; ++i)
                    #pragma unroll
                    for (int j = 0; j < 2; ++j)
                        acc[i][j] = __builtin_amdgcn_mfma_f32_16x16x32_bf16(afr[i], bfr[j], acc[i][j], 0, 0, 0);
            }
            __syncthreads();
        }
        float* P = part + (size_t)(ks * 4 + which) * 262144;
        #pragma unroll
        for (int j = 0; j < 2; ++j) {
            const int colp = n0 + cb + j * 16 + mrow;
            #pragma unroll
            for (int i = 0; i < 4; ++i)
                #pragma unroll
                for (int r = 0; r < 4; ++r) {
                    const int row = m0 + rb + i * 16 + q * 4 + r;
                    P[(size_t)row * 1024 + colp] = acc[i][j][r];
                }
        }
    } else if (blk < 1280) {
        // ---- transpose Wg,Wuf,Wui,Wuo -> wt planes 0..3 (64x64 tiles) ----
        const float* Ws[4] = {W_g, W_uf, W_ui, W_uo};
        const int t = blk - 256;
        const int plane = t >> 8;
        const int tt = t & 255;
        const int kb = (tt >> 4) * 64;
        const int nb = (tt & 15) * 64;
        const float* W = Ws[plane];
        bf16* Wt = wt + (size_t)plane * (1024 * 1024);
        float (*tl)[65] = (float (*)[65])sbuf;     // [64 k][65 n] padded

        #pragma unroll
        for (int it = 0; it < 4; ++it) {
            int lin = it * 256 + tid;
            int kr = lin >> 4, n4 = lin & 15;
            *(float4*)&tl[kr][n4 * 4] =
                *(const float4*)(W + (size_t)(kb + kr) * 1024 + nb + n4 * 4);
        }
        __syncthreads();
        #pragma unroll
        for (int it = 0; it < 2; ++it) {
            int lin = it * 256 + tid;
            int n = lin >> 3, k8 = (lin & 7) * 8;
            u16x8 p;
            #pragma unroll
            for (int j = 0; j < 8; ++j) p[j] = fbits(tl[k8 + j][n]);
            *(u16x8*)(Wt + (size_t)(nb + n) * 1024 + kb + k8) = p;
        }
    } else {
        // ---- cast h_state -> hbf, 16 elems/thread, ushort8 stores ----
        const int e = blk - 1280;
        size_t idx = ((size_t)e * 256 + tid) * 16;
        #pragma unroll
        for (int hh = 0; hh < 2; ++hh) {
            float4 a = *(const float4*)(h_state + idx + hh * 8);
            float4 b = *(const float4*)(h_state + idx + hh * 8 + 4);
            u16x8 p;
            p[0] = fbits(a.x); p[1] = fbits(a.y); p[2] = fbits(a.z); p[3] = fbits(a.w);
            p[4] = fbits(b.x); p[5] = fbits(b.y); p[6] = fbits(b.z); p[7] = fbits(b.w);
            *(u16x8*)(hbf + idx + hh * 8) = p;
        }
    }
}

// ---------------------------------------------------------------------------
// attention per (b,h) -> mpb bf16  (sums dense partials + b_emb)
// ---------------------------------------------------------------------------
__global__ __launch_bounds__(256) void k_attn(
    const float* __restrict__ m_state,
    const float* __restrict__ part,
    const float* __restrict__ b_emb,
    bf16* __restrict__ mp)
{
    const int b = blockIdx.x >> 3;
    const int h = blockIdx.x & 7;
    const int tid = threadIdx.x;

    __shared__ float kv[17][132];
    __shared__ float sc[16][18];

    for (int idx = tid; idx < 17 * 32; idx += 256) {
        int r = idx >> 5, d4 = idx & 31;
        float4 v;
        if (r < 16) {
            v = *(const float4*)&m_state[(size_t)(b * 16 + r) * 1024 + h * 128 + d4 * 4];
        } else {
            float4 v0 = *(const float4*)&part[(size_t)b * 1024 + h * 128 + d4 * 4];
            float4 v1 = *(const float4*)&part[(size_t)(4 * 256 + b) * 1024 + h * 128 + d4 * 4];
            float4 be = *(const float4*)&b_emb[h * 128 + d4 * 4];
            v.x = v0.x + v1.x + be.x;
            v.y = v0.y + v1.y + be.y;
            v.z = v0.z + v1.z + be.z;
            v.w = v0.w + v1.w + be.w;
        }
        *(float4*)&kv[r][d4 * 4] = v;
    }
    __syncthreads();

    for (int p = tid; p < 16 * 17; p += 256) {
        int qi = p / 17, ki = p % 17;
        float dx = 0.f, dy = 0.f, dz = 0.f, dw = 0.f;
        #pragma unroll 8
        for (int d4 = 0; d4 < 32; ++d4) {
            float4 a = *(const float4*)&kv[qi][d4 * 4];
            float4 c = *(const float4*)&kv[ki][d4 * 4];
            dx += a.x * c.x; dy += a.y * c.y; dz += a.z * c.z; dw += a.w * c.w;
        }
        sc[qi][ki] = (dx + dy + dz + dw) * 0.0883883476483184f;
    }
    __syncthreads();

    if (tid < 16) {
        float mx = -1e30f;
        for (int k = 0; k < 17; ++k) mx = fmaxf(mx, sc[tid][k]);
        float s = 0.0f;
        for (int k = 0; k < 17; ++k) { float e = __expf(sc[tid][k] - mx); sc[tid][k] = e; s += e; }
        float inv = 1.0f / s;
        for (int k = 0; k < 17; ++k) sc[tid][k] *= inv;
    }
    __syncthreads();

    for (int p = tid; p < 16 * 32; p += 256) {
        int qi = p >> 5, d4 = p & 31;
        float sx = 0.f, sy = 0.f, sz = 0.f, sw = 0.f;
        #pragma unroll
        for (int k = 0; k < 17; ++k) {
            float w = sc[qi][k];
            float4 v = *(const float4*)&kv[k][d4 * 4];
            sx += w * v.x; sy += w * v.y; sz += w * v.z; sw += w * v.w;
        }
        float4 base = *(const float4*)&kv[qi][d4 * 4];
        size_t off = (size_t)(b * 16 + qi) * 1024 + h * 128 + d4 * 4;
        mp[off + 0] = f2b(base.x + sx);
        mp[off + 1] = f2b(base.y + sy);
        mp[off + 2] = f2b(base.z + sz);
        mp[off + 3] = f2b(base.w + sw);
    }
}

// ---------------------------------------------------------------------------
// Unified big GEMM: M=4096, N=4096 (3 gate planes + g plane), K=1024.
// 256 blocks (1/CU), 512 thr (8 waves 2Mx4N), 256x256 tile, BK=64.
// Double-buffered LDS (128 KB dyn), counted vmcnt(8) + raw s_barrier,
// T2 xor-swizzle: linear LDS dest, source chunk c8^r8, reads ^((row&7)<<4).
// C-write: LDS round-trip (stride 264) -> coalesced ushort8 stores.
// ---------------------------------------------------------------------------
__global__ __launch_bounds__(512, 2) void k_gemm_big(
    const bf16* __restrict__ hbf,
    const bf16* __restrict__ mpb,
    const bf16* __restrict__ wt,
    bf16* __restrict__ pre,
    bf16* __restrict__ preg)
{
    extern __shared__ __align__(16) char smem[];   // A0@0 B0@32K A1@64K B1@96K

    int bid = blockIdx.x;
    bid = (bid & 7) * 32 + (bid >> 3);             // XCD-chunked swizzle (256%8==0)
    const int by = bid & 15;                        // row tile   (chunk shares B cols)
    const int ct = bid >> 4;                        // col tile 0..15
    const int m0 = by * 256;

    const bf16* A; const bf16* Bp; bf16* Cout; int bn0;
    if (ct < 12) {
        A = hbf;
        const int g = ct >> 2;                      // 0=f,1=i,2=o
        bn0 = (ct & 3) * 256;
        Bp = wt + (size_t)(1 + g) * (1024 * 1024);
        Cout = pre + (size_t)g * (4096 * 1024);
    } else {
        A = mpb;
        bn0 = (ct - 12) * 256;
        Bp = wt;                                    // plane 0 = W_g
        Cout = preg;
    }

    const int wv = threadIdx.x >> 6;
    const int lane = threadIdx.x & 63;
    const int r8 = lane >> 3, c8 = lane & 7;
    const int mrow = lane & 15, q = lane >> 4;
    const int wr = wv >> 2, wc = wv & 3;            // wave tile 128x64

    const f32x4 zero4 = {0.0f, 0.0f, 0.0f, 0.0f};
    f32x4 acc[8][4];
    #pragma unroll
    for (int i = 0; i < 8; ++i)
        #pragma unroll
        for (int j = 0; j < 4; ++j) acc[i][j] = zero4;

    auto STAGE = [&](int buf, int k0) {
        char* sA = smem + buf * 65536;
        char* sB = sA + 32768;
        #pragma unroll
        for (int t = 0; t < 4; ++t) {
            const int rr = wv * 32 + t * 8;
            gl_lds16(A  + (size_t)(m0  + rr + r8) * 1024 + k0 + (c8 ^ r8) * 8, sA + rr * 128);
            gl_lds16(Bp + (size_t)(bn0 + rr + r8) * 1024 + k0 + (c8 ^ r8) * 8, sB + rr * 128);
        }
    };

    STAGE(0, 0);

    #pragma unroll 2
    for (int step = 0; step < 16; ++step) {
        const int cur = step & 1;
        if (step < 15) {
            STAGE(cur ^ 1, (step + 1) * 64);
            asm volatile("s_waitcnt vmcnt(8)" ::: "memory");   // prev tile landed
        } else {
            asm volatile("s_waitcnt vmcnt(0)" ::: "memory");
        }
        __builtin_amdgcn_s_barrier();
        __builtin_amdgcn_sched_barrier(0);

        const char* sA = smem + cur * 65536;
        const char* sB = sA + 32768;
        #pragma unroll
        for (int kk = 0; kk < 2; ++kk) {
            const int kb = kk * 64 + q * 16;
            bf16x8 afr[8], bfr[4];
            #pragma unroll
            for (int i = 0; i < 8; ++i) {
                const int row = wr * 128 + i * 16 + mrow;
                afr[i] = *(const bf16x8*)(sA + row * 128 + (kb ^ ((row & 7) << 4)));
            }
            #pragma unroll
            for (int j = 0; j < 4; ++j) {
                const int n = wc * 64 + j * 16 + mrow;
                bfr[j] = *(const bf16x8*)(sB + n * 128 + (kb ^ ((n & 7) << 4)));
            }
            #pragma unroll
            for (int i = 0; i < 8; ++i)
                #pragma unroll
                for (int j = 0; j < 4; ++j)
                    acc[i][j] = __builtin_amdgcn_mfma_f32_16x16x32_bf16(afr[i], bfr[j], acc[i][j], 0, 0, 0);
        }
        __builtin_amdgcn_sched_barrier(0);
        __builtin_amdgcn_s_barrier();
    }

    // ---- coalesced C-write: 2 chunks of 128 rows x 256 cols via LDS ----
    bf16* sC = (bf16*)smem;
    const int CS = 264;                       // row stride elems (528B, bank shift 4)
    #pragma unroll
    for (int chunk = 0; chunk < 2; ++chunk) {
        __syncthreads();
        if (wr == chunk) {
            #pragma unroll
            for (int i = 0; i < 8; ++i)
                #pragma unroll
                for (int j = 0; j < 4; ++j)
                    #pragma unroll
                    for (int r = 0; r < 4; ++r) {
                        const int row = i * 16 + q * 4 + r;       // 0..127
                        const int col = wc * 64 + j * 16 + mrow;  // 0..255
                        sC[row * CS + col] = f2b(acc[i][j][r]);
                    }
        }
        __syncthreads();
        #pragma unroll
        for (int ps = 0; ps < 8; ++ps) {
            const int row = ps * 16 + (threadIdx.x >> 5);
            const int cc = (threadIdx.x & 31) * 8;
            u16x8 v = *(const u16x8*)(sC + row * CS + cc);
            *(u16x8*)(Cout + (size_t)(m0 + chunk * 128 + row) * 1024 + bn0 + cc) = v;
        }
    }
}

// ---------------------------------------------------------------------------
// Epilogue: elementwise over 4M outputs, 4 elems/thread, coalesced.
// x-gate terms are sums of 2 K-split partials.
// ---------------------------------------------------------------------------
__global__ __launch_bounds__(256) void k_epi(
    const float* __restrict__ m_state,
    const bf16* __restrict__ mpb,
    const bf16* __restrict__ preg,
    const bf16* __restrict__ pre,     // 3 planes
    const float* __restrict__ part,   // [2][4][256][1024]
    const float* __restrict__ b_g, const float* __restrict__ b_uf,
    const float* __restrict__ b_ui, const float* __restrict__ b_uo,
    float* __restrict__ out_mem, float* __restrict__ out_hid)
{
    const int idx = (blockIdx.x * 256 + threadIdx.x) * 4;
    const int row = idx >> 10;
    const int col = idx & 1023;
    const int b = row >> 4;

    float4 m4  = *(const float4*)(m_state + idx);
    float4 mp4 = ld_bf4(mpb + idx);
    float4 pg4 = ld_bf4(preg + idx);
    float4 pf4 = ld_bf4(pre + idx);
    float4 pi4 = ld_bf4(pre + 4194304 + idx);
    float4 po4 = ld_bf4(pre + 8388608 + idx);

    const size_t po = (size_t)b * 1024 + col;
    float4 xfa = *(const float4*)(part + 262144 + po);
    float4 xfb = *(const float4*)(part + 1048576 + 262144 + po);
    float4 xia = *(const float4*)(part + 524288 + po);
    float4 xib = *(const float4*)(part + 1048576 + 524288 + po);
    float4 xoa = *(const float4*)(part + 786432 + po);
    float4 xob = *(const float4*)(part + 1048576 + 786432 + po);
    float4 xf4, xi4, xo4;
    xf4.x = xfa.x + xfb.x; xf4.y = xfa.y + xfb.y; xf4.z = xfa.z + xfb.z; xf4.w = xfa.w + xfb.w;
    xi4.x = xia.x + xib.x; xi4.y = xia.y + xib.y; xi4.z = xia.z + xib.z; xi4.w = xia.w + xib.w;
    xo4.x = xoa.x + xob.x; xo4.y = xoa.y + xob.y; xo4.z = xoa.z + xob.z; xo4.w = xoa.w + xob.w;

    float4 bg4 = *(const float4*)(b_g + col);
    float4 bf4 = *(const float4*)(b_uf + col);
    float4 bi4 = *(const float4*)(b_ui + col);
    float4 bo4 = *(const float4*)(b_uo + col);

    float4 om, oh;
    {
        float mp2 = pg4.x + bg4.x + mp4.x;
        float fg = sig(pf4.x + bf4.x + xf4.x);
        float ig = sig(pi4.x + bi4.x + xi4.x);
        float og = sig(po4.x + bo4.x + xo4.x);
        om.x = sig(m4.x * fg + 1.0f) + mp2 * sig(ig);
        oh.x = ftanh(m4.x) * sig(og);
    }
    {
        float mp2 = pg4.y + bg4.y + mp4.y;
        float fg = sig(pf4.y + bf4.y + xf4.y);
        float ig = sig(pi4.y + bi4.y + xi4.y);
        float og = sig(po4.y + bo4.y + xo4.y);
        om.y = sig(m4.y * fg + 1.0f) + mp2 * sig(ig);
        oh.y = ftanh(m4.y) * sig(og);
    }
    {
        float mp2 = pg4.z + bg4.z + mp4.z;
        float fg = sig(pf4.z + bf4.z + xf4.z);
        float ig = sig(pi4.z + bi4.z + xi4.z);
        float og = sig(po4.z + bo4.z + xo4.z);
        om.z = sig(m4.z * fg + 1.0f) + mp2 * sig(ig);
        oh.z = ftanh(m4.z) * sig(og);
    }
    {
        float mp2 = pg4.w + bg4.w + mp4.w;
        float fg = sig(pf4.w + bf4.w + xf4.w);
        float ig = sig(pi4.w + bi4.w + xi4.w);
        float og = sig(po4.w + bo4.w + xo4.w);
        om.w = sig(m4.w * fg + 1.0f) + mp2 * sig(ig);
        oh.w = ftanh(m4.w) * sig(og);
    }

    *(float4*)(out_mem + idx) = om;
    *(float4*)(out_hid + idx) = oh;
}

extern "C" void kernel_launch(void* const* d_in, const int* in_sizes, int n_in,
                              void* d_out, int out_size, void* d_ws, size_t ws_size,
                              hipStream_t stream)
{
    const float* inputs  = (const float*)d_in[0];
    const float* h_state = (const float*)d_in[1];
    const float* m_state = (const float*)d_in[2];
    const float* W_emb   = (const float*)d_in[3];
    const float* b_emb   = (const float*)d_in[4];
    const float* W_g     = (const float*)d_in[5];
    const float* b_g     = (const float*)d_in[6];
    const float* W_wf    = (const float*)d_in[7];
    const float* W_wi    = (const float*)d_in[8];
    const float* W_wo    = (const float*)d_in[9];
    const float* W_uf    = (const float*)d_in[10];
    const float* b_uf    = (const float*)d_in[11];
    const float* W_ui    = (const float*)d_in[12];
    const float* b_ui    = (const float*)d_in[13];
    const float* W_uo    = (const float*)d_in[14];
    const float* b_uo    = (const float*)d_in[15];

    char* wsb = (char*)d_ws;
    float* part = (float*)wsb;                           // 8 MB
    bf16*  hbf  = (bf16*)(wsb + 8u  * 1048576u);         // 8 MB
    bf16*  mpb  = (bf16*)(wsb + 16u * 1048576u);         // 8 MB
    bf16*  wt   = (bf16*)(wsb + 24u * 1048576u);         // 8 MB (4 planes)
    bf16*  pre  = (bf16*)(wsb + 32u * 1048576u);         // 24 MB (3 planes)
    bf16*  preg = (bf16*)(wsb + 56u * 1048576u);         // 8 MB

    float* out_mem = (float*)d_out;
    float* out_hid = out_mem + (size_t)4096 * 1024;

    // prep: 256 x-proj + 1024 transpose + 1024 h-cast
    k_prep<<<dim3(2304), dim3(256), 0, stream>>>(
        W_g, W_uf, W_ui, W_uo, W_emb, W_wf, W_wi, W_wo,
        h_state, inputs, wt, hbf, part);

    // attention -> mpb
    k_attn<<<dim3(256 * 8), dim3(256), 0, stream>>>(m_state, part, b_emb, mpb);

    // unified gates + g GEMM (256 blocks, 512 thr, 128 KB dynamic LDS)
    k_gemm_big<<<dim3(256), dim3(512), 131072, stream>>>(hbf, mpb, wt, pre, preg);

    // epilogue -> outputs
    k_epi<<<dim3(4096), dim3(256), 0, stream>>>(
        m_state, mpb, preg, pre, part,
        b_g, b_uf, b_ui, b_uo, out_mem, out_hid);
}